// Round 8
// baseline (158.293 us; speedup 1.0000x reference)
//
#include <hip/hip_runtime.h>

// VQ via MFMA: x (32,64,64,64) fp32 NCHW, embed (512,64) fp32.
// fp16 MFMA approx dists (err ~0.18 << EPS 0.5), exact fp32 recheck of
// near-min candidates (bit-identical dot+esq formulas) -> exact argmin.
//
// R19 post-mortem: pipeline (P-reg async stage + dbuf + barrier cut) at
// VGPR 128 / no spill -> 67.5us. SIX structures now land 65-69us
// (blocks 512-4096, occ 18-67%, 1-2 dispatches, 2x MFMA, reg/LDS B,
// pipelined or not); all pipes <30%. Serial latency model ~21us@2.4GHz;
// 67us consistent with ~50k cyc at idle-DPM clock (~800MHz; dispatches
// are isolated by ~200ms host gaps -> no ramp). Clock uncontrollable;
// cycles are. Shared residue of all six: 4-wave barrier-coupled block
// with cross-wave combine.
//
// R20 DECISIVE: wave-autonomous, ZERO-barrier kernel. Each wave owns
// 16 rows x all 512 codes: A direct from global (XsH deleted), B/esq via
// verified depth-2 LOADB from prep'd EH, queue/recheck/epilogue all
// wave-private (same LDS-atomic pattern, now per-wave). No __syncthreads
// anywhere. Numerics conserved exactly (same keys, EPS strictly tighter
// with global g1, same fp32 recheck chain + esq).
// Predict: theory right -> dur 25-40us, VALUBusy 50%+, occ 40-50%.
// Tripwires: WRITE 33.3MB, VGPR<=128. If 65-69 again -> external floor;
// declare roofline-of-structure next round.

#define VQ_N 131072
#define VQ_D 64
#define VQ_K 512
#define VQ_HW 4096
#define WROWS 16         // rows per wave
#define NW 4             // waves per block; grid = N/(WROWS*NW) = 2048
#define EPS 0.5f         // prune margin; fp16 worst-case err ~0.18, typ ~0.01
#define QW 128           // queue entries per wave (slots 0..15 = row winners)
#define X32_STR 69       // floats/row: ODD -> low-conflict scalar access

typedef __attribute__((ext_vector_type(8))) _Float16 half8;
typedef __attribute__((ext_vector_type(4))) float f32x4;

// order-preserving float->uint for the exact-recheck u64 key
static __device__ __forceinline__ unsigned fenc(float f) {
    unsigned u = __float_as_uint(f);
    return u ^ ((unsigned)(((int)u) >> 31) | 0x80000000u);
}
// clear low 9 mantissa bits (decode of embedded-index float keys)
static __device__ __forceinline__ float clr9(float f) {
    return __uint_as_float(__float_as_uint(f) & 0xFFFFFE00u);
}

// prep: embed fp32 -> fp16 (EH); first 512 threads also do e_sq (verified)
__global__ __launch_bounds__(256) void vq_prep_kernel(
    const float* __restrict__ embed,
    _Float16* __restrict__ EH, float* __restrict__ esq) {
    int g = blockIdx.x * 256 + threadIdx.x;   // 32768 elems
    EH[g] = (_Float16)embed[g];
    if (g < VQ_K) {
        const float* e = embed + g * VQ_D;
        float p0 = 0.f, p1 = 0.f, p2 = 0.f, p3 = 0.f;
#pragma unroll
        for (int d = 0; d < VQ_D; d += 4) {
            p0 = fmaf(e[d + 0], e[d + 0], p0);
            p1 = fmaf(e[d + 1], e[d + 1], p1);
            p2 = fmaf(e[d + 2], e[d + 2], p2);
            p3 = fmaf(e[d + 3], e[d + 3], p3);
        }
        esq[g] = (p0 + p1) + (p2 + p3);
    }
}

// load B fragment + esq for code-tile nt (wave covers ALL 512 codes: nb=0)
#define LOADB(nt, F0, F1, ES) {                                    \
    int _eo = (((nt) << 4) + lrow) * VQ_D + (quad << 3);           \
    F0 = *(const half8*)&EH[_eo];                                  \
    F1 = *(const half8*)&EH[_eo + 32];                             \
    ES = esq[((nt) << 4) + lrow]; }

// 2-MFMA fp16 dist + 4-VALU key update (verified R12-R19 numerics)
#define PROC(nt, F0, F1, ES) {                                                 \
    f32x4 acc = {0.f, 0.f, 0.f, 0.f};                                          \
    acc = __builtin_amdgcn_mfma_f32_16x16x32_f16(AH0, F0, acc, 0, 0, 0);       \
    acc = __builtin_amdgcn_mfma_f32_16x16x32_f16(AH1, F1, acc, 0, 0, 0);       \
    unsigned _nn = (unsigned)(((nt) << 4) + lrow);   /* global code id */      \
    _Pragma("unroll")                                                          \
    for (int i = 0; i < 4; ++i) {      /* C: col(n)=lane&15, row=quad*4+i */   \
        float v = fmaf(-2.f, acc[i], ES);                                      \
        float kf = __uint_as_float((__float_as_uint(v) & 0xFFFFFE00u) | _nn);  \
        m2[i] = __builtin_amdgcn_fmed3f(kf, m1[i], m2[i]);                     \
        m1[i] = fminf(m1[i], kf);                                              \
    } }

__global__ __launch_bounds__(256, 2) void vq_wave_kernel(
    const float* __restrict__ x, const float* __restrict__ embed,
    const float* __restrict__ esq, const _Float16* __restrict__ EH,
    float* __restrict__ out_q, float* __restrict__ out_idx) {
    // ALL per-wave private regions; no cross-wave sharing, no barriers.
    __shared__ float Xs32[NW][WROWS * X32_STR];          // 17664 B
    __shared__ unsigned long long row_best[NW][WROWS];   // 512 B
    __shared__ int qcnt[NW];
    __shared__ unsigned short qbuf[NW][QW];              // 1024 B

    const int t    = threadIdx.x;
    const int lane = t & 63;
    const int wave = t >> 6;
    const int lrow = lane & 15;
    const int quad = lane >> 4;

    const int n0 = blockIdx.x * (WROWS * NW) + wave * WROWS;  // wave's rows
    const int b  = n0 >> 12;         // 64 | 4096 -> wave stays in one image
    const int hw0 = n0 & 4095;

    // ---- B prefetch slots (verified depth-2 pattern) ----
    half8 fa0, fa1, fb0, fb1;
    float esa, esb;
    LOADB(0, fa0, fa1, esa)
    LOADB(1, fb0, fb1, esb)

    // ---- A direct from global: lane (lrow=row, quad) loads 16 fp32 ----
    const float* xb = x + (size_t)b * (VQ_D * VQ_HW) + hw0 + lrow;
    float f0[8], f1[8];
#pragma unroll
    for (int dd = 0; dd < 8; ++dd) f0[dd] = xb[(quad * 8 + dd) * VQ_HW];
#pragma unroll
    for (int dd = 0; dd < 8; ++dd) f1[dd] = xb[(quad * 8 + 32 + dd) * VQ_HW];

    half8 AH0, AH1;                      // fp16 A-frags (same RTE casts)
#pragma unroll
    for (int dd = 0; dd < 8; ++dd) {
        AH0[dd] = (_Float16)f0[dd];
        AH1[dd] = (_Float16)f1[dd];
    }
    // stage exact fp32 x rows for recheck (wave-private region)
    {
        float* xs = &Xs32[wave][lrow * X32_STR];
#pragma unroll
        for (int dd = 0; dd < 8; ++dd) xs[quad * 8 + dd] = f0[dd];
#pragma unroll
        for (int dd = 0; dd < 8; ++dd) xs[quad * 8 + 32 + dd] = f1[dd];
    }
    if (lane < WROWS) row_best[wave][lane] = ~0ull;
    if (lane == 0) qcnt[wave] = WROWS;   // slots 0..15 reserved for winners
    asm volatile("s_waitcnt lgkmcnt(0)");   // drain wave's DS writes/inits

    float m1[4], m2[4];
#pragma unroll
    for (int i = 0; i < 4; ++i) {
        m1[i] = __uint_as_float(0x7F800000u);   // +inf (low 9 bits 0)
        m2[i] = __uint_as_float(0x7F800000u);
    }

    // ---- main loop: 32 code-tiles (all 512 codes), depth-2 prefetch ----
#pragma unroll 1
    for (int nt = 0; nt < 32; nt += 2) {
        PROC(nt, fa0, fa1, esa)
        int n2 = (nt + 2 < 32) ? nt + 2 : 31;   // clamped harmless reload
        LOADB(n2, fa0, fa1, esa)
        PROC(nt + 1, fb0, fb1, esb)
        int n3 = (nt + 3 < 32) ? nt + 3 : 31;
        LOADB(n3, fb0, fb1, esb)
    }

    // ---- row-min over the 16 n-lanes (stays within 16-lane groups) ----
    float g1[4];
#pragma unroll
    for (int i = 0; i < 4; ++i) g1[i] = m1[i];
#pragma unroll
    for (int s = 1; s <= 8; s <<= 1)
#pragma unroll
        for (int i = 0; i < 4; ++i)
            g1[i] = fminf(g1[i], __shfl_xor(g1[i], s));

    // ---- push candidates: winner -> fixed slot m (keys unique over 512
    //      codes -> exactly one lane matches g1); near-ties -> slots 16+ ----
#pragma unroll
    for (int i = 0; i < 4; ++i) {
        int m = quad * 4 + i;                  // wave-local row 0..15
        float thr = clr9(g1[i]) + EPS;
        if (m1[i] == g1[i]) {
            qbuf[wave][m] = (unsigned short)
                (((unsigned)m << 9) | (__float_as_uint(m1[i]) & 511u));
        } else if (clr9(m1[i]) <= thr) {
            int id = atomicAdd(&qcnt[wave], 1);
            if (id < QW)
                qbuf[wave][id] = (unsigned short)
                    (((unsigned)m << 9) | (__float_as_uint(m1[i]) & 511u));
        }
        if (clr9(m2[i]) <= thr) {
            int id = atomicAdd(&qcnt[wave], 1);
            if (id < QW)
                qbuf[wave][id] = (unsigned short)
                    (((unsigned)m << 9) | (__float_as_uint(m2[i]) & 511u));
        }
    }
    asm volatile("s_waitcnt lgkmcnt(0)");   // wave-local queue visible

    // ---- exact fp32 recheck (same fmaf order as R1 kernel), wave-local ----
    int qc = atomicAdd(&qcnt[wave], 0);
    if (qc > QW) qc = QW;
    for (int qi = lane; qi < qc; qi += 64) {
        unsigned e = qbuf[wave][qi];
        int m = (int)(e >> 9), n = (int)(e & 511u);
        const float4* er = (const float4*)(embed + n * VQ_D);
        const float* xr = &Xs32[wave][m * X32_STR];
        float dot = 0.f;
#pragma unroll
        for (int d4 = 0; d4 < 16; ++d4) {
            float4 ev = er[d4];
            dot = fmaf(xr[4 * d4 + 0], ev.x, dot);
            dot = fmaf(xr[4 * d4 + 1], ev.y, dot);
            dot = fmaf(xr[4 * d4 + 2], ev.z, dot);
            dot = fmaf(xr[4 * d4 + 3], ev.w, dot);
        }
        float v = fmaf(-2.f, dot, esq[n]);
        unsigned long long key =
            (((unsigned long long)fenc(v)) << 32) | (unsigned)n;
        atomicMin(&row_best[wave][m], key);  // exact; tie -> smaller n
    }
    asm volatile("s_waitcnt lgkmcnt(0)");   // all this wave's atomics done

    // ---- epilogue (wave-private): indices + coalesced quantized rows ----
    if (lane < WROWS)
        out_idx[n0 + lane] =
            (float)(unsigned)(row_best[wave][lane] & 0xffffffffu);

#pragma unroll
    for (int it = 0; it < 4; ++it) {
        int o   = it * 256 + lane * 4;   // 16 rows x 64 floats, contiguous
        int row = o >> 6;
        int col = o & 63;
        unsigned k = (unsigned)(row_best[wave][row] & 0xffffffffu);
        float4 val = *(const float4*)(embed + k * VQ_D + col);
        *(float4*)(out_q + (size_t)n0 * VQ_D + o) = val;
    }
}

extern "C" void kernel_launch(void* const* d_in, const int* in_sizes, int n_in,
                              void* d_out, int out_size, void* d_ws, size_t ws_size,
                              hipStream_t stream) {
    const float* x     = (const float*)d_in[0];
    const float* embed = (const float*)d_in[1];
    float* out_q   = (float*)d_out;
    float* out_idx = (float*)d_out + (size_t)VQ_N * VQ_D;

    float* esq    = (float*)d_ws;                           // 512 f
    _Float16* EH  = (_Float16*)((char*)d_ws + 2048);        // 512*64 f16

    vq_prep_kernel<<<(VQ_K * VQ_D) / 256, 256, 0, stream>>>(embed, EH, esq);
    vq_wave_kernel<<<VQ_N / (WROWS * NW), 256, 0, stream>>>(
        x, embed, esq, EH, out_q, out_idx);
}

// Round 9
// 103.566 us; speedup vs baseline: 1.5284x; 1.5284x over previous
//
#include <hip/hip_runtime.h>

// VQ via MFMA: x (32,64,64,64) fp32 NCHW, embed (512,64) fp32.
// fp16 MFMA approx dists (err ~0.18 << EPS 0.5), exact fp32 recheck of
// near-min candidates (bit-identical dot+esq formulas) -> exact argmin.
//
// R20 post-mortem: zero-barrier wave-autonomous kernel REGRESSED 67->89us
// (VALUBusy 18, occ 51). Causes: (1) hot loop lost R17's B-in-regs ->
// per-tile EH loads from L2 with only 2 MFMA+16 VALU cover at depth 2,
// AND LOADB frag addressing scattered (16B/lane @128B stride, 8KB span
// per instr); (2) WROWS=16 halved tail amortization. Occupancy 51% with
// worse dur = final confirmation wave-slots were never the resource.
//
// R21 = R20 repaired: (1) EH2 FRAG-MAJOR codebook (prep reorders) ->
// LOADB is one contiguous 2KB read per wave; (2) WROWS 32 (2 rt) ->
// 4 MFMA + 32 VALU per tile; (3) depth-4 prefetch (R12-verified) ->
// ~600-800cy in flight >= L2 latency. Still ZERO __syncthreads; queue/
// recheck/epilogue wave-private (R20-verified); numerics byte-identical.
// Predict: VGPR 100-125 (WRITE 33.3MB tripwire), LDS 38.4KB, dur 35-48us
// if decoupling+covered-loop is the lever; 60-70 -> declare floor next.

#define VQ_N 131072
#define VQ_D 64
#define VQ_K 512
#define VQ_HW 4096
#define WROWS 32         // rows per wave
#define NW 4             // waves per block; grid = N/(WROWS*NW) = 1024
#define EPS 0.5f         // prune margin; fp16 worst-case err ~0.18, typ ~0.01
#define QW 256           // queue entries per wave (slots 0..31 = row winners)
#define X32_STR 69       // floats/row: ODD -> low-conflict access

typedef __attribute__((ext_vector_type(8))) _Float16 half8;
typedef __attribute__((ext_vector_type(4))) float f32x4;

// order-preserving float->uint for the exact-recheck u64 key
static __device__ __forceinline__ unsigned fenc(float f) {
    unsigned u = __float_as_uint(f);
    return u ^ ((unsigned)(((int)u) >> 31) | 0x80000000u);
}
// clear low 9 mantissa bits (decode of embedded-index float keys)
static __device__ __forceinline__ float clr9(float f) {
    return __uint_as_float(__float_as_uint(f) & 0xFFFFFE00u);
}

// prep: embed fp32 -> FRAG-MAJOR fp16 EH2 + e_sq (esq formula verified).
// EH2 element g encodes: j=g&15 (elem in lane's 16), lp=g>>4, l=lp&63
// (lane), nt=lp>>6 (code-tile). Lane l of tile nt consumes code
// nt*16+(l&15), d = (j>>3)*32 + (l>>4)*8 + (j&7).
__global__ __launch_bounds__(256) void vq_prep_kernel(
    const float* __restrict__ embed,
    _Float16* __restrict__ EH2, float* __restrict__ esq) {
    int g  = blockIdx.x * 256 + threadIdx.x;   // 32768 elems
    int j  = g & 15;
    int lp = g >> 4;
    int l  = lp & 63;
    int nt = lp >> 6;
    int src = (nt * 16 + (l & 15)) * VQ_D + (j >> 3) * 32 + ((l >> 4) << 3)
              + (j & 7);
    EH2[g] = (_Float16)embed[src];
    if (g < VQ_K) {
        const float* e = embed + g * VQ_D;
        float p0 = 0.f, p1 = 0.f, p2 = 0.f, p3 = 0.f;
#pragma unroll
        for (int d = 0; d < VQ_D; d += 4) {
            p0 = fmaf(e[d + 0], e[d + 0], p0);
            p1 = fmaf(e[d + 1], e[d + 1], p1);
            p2 = fmaf(e[d + 2], e[d + 2], p2);
            p3 = fmaf(e[d + 3], e[d + 3], p3);
        }
        esq[g] = (p0 + p1) + (p2 + p3);
    }
}

// load B fragment pair + esq for code-tile nt: 32B contiguous per lane,
// 2KB contiguous per wave (frag-major EH2)
#define LOADB(nt, F0, F1, ES) {                                    \
    const half8* _p = (const half8*)(EH2 + ((((nt) << 6) + lane) << 4)); \
    F0 = _p[0];                                                    \
    F1 = _p[1];                                                    \
    ES = esq[((nt) << 4) + lrow]; }

// 2-MFMA fp16 dist for row-tile rt + 4-VALU key update (verified numerics)
#define PROC1(nt, rt, F0, F1, ES) {                                            \
    f32x4 acc = {0.f, 0.f, 0.f, 0.f};                                          \
    acc = __builtin_amdgcn_mfma_f32_16x16x32_f16(AH##rt##0, F0, acc, 0, 0, 0); \
    acc = __builtin_amdgcn_mfma_f32_16x16x32_f16(AH##rt##1, F1, acc, 0, 0, 0); \
    unsigned _nn = (unsigned)(((nt) << 4) + lrow);   /* global code id */      \
    _Pragma("unroll")                                                          \
    for (int i = 0; i < 4; ++i) {      /* C: col(n)=lane&15, row=quad*4+i */   \
        float v = fmaf(-2.f, acc[i], ES);                                      \
        float kf = __uint_as_float((__float_as_uint(v) & 0xFFFFFE00u) | _nn);  \
        m2[rt][i] = __builtin_amdgcn_fmed3f(kf, m1[rt][i], m2[rt][i]);         \
        m1[rt][i] = fminf(m1[rt][i], kf);                                      \
    } }

#define PROC2(nt, F0, F1, ES)        \
    PROC1(nt, 0, F0, F1, ES)         \
    PROC1(nt, 1, F0, F1, ES)

__global__ __launch_bounds__(256, 2) void vq_wave_kernel(
    const float* __restrict__ x, const float* __restrict__ embed,
    const float* __restrict__ esq, const _Float16* __restrict__ EH2,
    float* __restrict__ out_q, float* __restrict__ out_idx) {
    // ALL per-wave private regions; no cross-wave sharing, no barriers.
    __shared__ float Xs32[NW][WROWS * X32_STR];          // 35328 B
    __shared__ unsigned long long row_best[NW][WROWS];   // 1024 B
    __shared__ int qcnt[NW];
    __shared__ unsigned short qbuf[NW][QW];              // 2048 B

    const int t    = threadIdx.x;
    const int lane = t & 63;
    const int wave = t >> 6;
    const int lrow = lane & 15;
    const int quad = lane >> 4;

    const int n0 = blockIdx.x * (WROWS * NW) + wave * WROWS;  // wave's rows
    const int b  = n0 >> 12;         // 128 | 4096 -> block stays in one image
    const int hw0 = n0 & 4095;

    // ---- B prefetch depth 4 (R12-verified pattern) ----
    half8 fa0, fa1, fb0, fb1, fc0, fc1, fd0, fd1;
    float esa, esb, esc, esd;
    LOADB(0, fa0, fa1, esa)
    LOADB(1, fb0, fb1, esb)
    LOADB(2, fc0, fc1, esc)
    LOADB(3, fd0, fd1, esd)

    // ---- A direct from global: 2 row-tiles (rows lrow, 16+lrow) ----
    const float* xb = x + (size_t)b * (VQ_D * VQ_HW) + hw0 + lrow;
    float f0[8], f1[8], f2[8], f3[8];
#pragma unroll
    for (int dd = 0; dd < 8; ++dd) {
        f0[dd] = xb[(quad * 8 + dd) * VQ_HW];
        f1[dd] = xb[(quad * 8 + 32 + dd) * VQ_HW];
        f2[dd] = xb[16 + (quad * 8 + dd) * VQ_HW];
        f3[dd] = xb[16 + (quad * 8 + 32 + dd) * VQ_HW];
    }
    half8 AH00, AH01, AH10, AH11;        // fp16 A-frags (same RTE casts)
#pragma unroll
    for (int dd = 0; dd < 8; ++dd) {
        AH00[dd] = (_Float16)f0[dd];
        AH01[dd] = (_Float16)f1[dd];
        AH10[dd] = (_Float16)f2[dd];
        AH11[dd] = (_Float16)f3[dd];
    }
    // stage exact fp32 x rows for recheck (wave-private region)
    {
        float* xs0 = &Xs32[wave][lrow * X32_STR];
        float* xs1 = &Xs32[wave][(16 + lrow) * X32_STR];
#pragma unroll
        for (int dd = 0; dd < 8; ++dd) {
            xs0[quad * 8 + dd]      = f0[dd];
            xs0[quad * 8 + 32 + dd] = f1[dd];
            xs1[quad * 8 + dd]      = f2[dd];
            xs1[quad * 8 + 32 + dd] = f3[dd];
        }
    }
    if (lane < WROWS) row_best[wave][lane] = ~0ull;
    if (lane == 0) qcnt[wave] = WROWS;   // slots 0..31 reserved for winners
    asm volatile("s_waitcnt lgkmcnt(0)");   // drain wave's DS writes/inits

    float m1[2][4], m2[2][4];
#pragma unroll
    for (int rt = 0; rt < 2; ++rt)
#pragma unroll
        for (int i = 0; i < 4; ++i) {
            m1[rt][i] = __uint_as_float(0x7F800000u);   // +inf (low 9 bits 0)
            m2[rt][i] = __uint_as_float(0x7F800000u);
        }

    // ---- main loop: 32 code-tiles (all 512 codes), depth-4 prefetch ----
#pragma unroll 1
    for (int nt = 0; nt < 32; nt += 4) {
        PROC2(nt, fa0, fa1, esa)
        int n4 = (nt + 4 < 32) ? nt + 4 : 31;   // clamped harmless reload
        LOADB(n4, fa0, fa1, esa)
        PROC2(nt + 1, fb0, fb1, esb)
        int n5 = (nt + 5 < 32) ? nt + 5 : 31;
        LOADB(n5, fb0, fb1, esb)
        PROC2(nt + 2, fc0, fc1, esc)
        int n6 = (nt + 6 < 32) ? nt + 6 : 31;
        LOADB(n6, fc0, fc1, esc)
        PROC2(nt + 3, fd0, fd1, esd)
        int n7 = (nt + 7 < 32) ? nt + 7 : 31;
        LOADB(n7, fd0, fd1, esd)
    }

    // ---- row-min over the 16 n-lanes (closed 16-lane xor groups) ----
    float g1[2][4];
#pragma unroll
    for (int rt = 0; rt < 2; ++rt)
#pragma unroll
        for (int i = 0; i < 4; ++i) g1[rt][i] = m1[rt][i];
#pragma unroll
    for (int s = 1; s <= 8; s <<= 1)
#pragma unroll
        for (int rt = 0; rt < 2; ++rt)
#pragma unroll
            for (int i = 0; i < 4; ++i)
                g1[rt][i] = fminf(g1[rt][i], __shfl_xor(g1[rt][i], s));

    // ---- push candidates: winner -> fixed slot m (keys unique over 512
    //      codes -> exactly one lane matches g1); near-ties -> slots 32+ ----
#pragma unroll
    for (int rt = 0; rt < 2; ++rt)
#pragma unroll
        for (int i = 0; i < 4; ++i) {
            int m = rt * 16 + quad * 4 + i;        // wave-local row 0..31
            float thr = clr9(g1[rt][i]) + EPS;
            if (m1[rt][i] == g1[rt][i]) {
                qbuf[wave][m] = (unsigned short)
                    (((unsigned)m << 9) | (__float_as_uint(m1[rt][i]) & 511u));
            } else if (clr9(m1[rt][i]) <= thr) {
                int id = atomicAdd(&qcnt[wave], 1);
                if (id < QW)
                    qbuf[wave][id] = (unsigned short)
                        (((unsigned)m << 9) |
                         (__float_as_uint(m1[rt][i]) & 511u));
            }
            if (clr9(m2[rt][i]) <= thr) {
                int id = atomicAdd(&qcnt[wave], 1);
                if (id < QW)
                    qbuf[wave][id] = (unsigned short)
                        (((unsigned)m << 9) |
                         (__float_as_uint(m2[rt][i]) & 511u));
            }
        }
    asm volatile("s_waitcnt lgkmcnt(0)");   // wave-local queue visible

    // ---- exact fp32 recheck (same fmaf order as R1 kernel), wave-local ----
    int qc = atomicAdd(&qcnt[wave], 0);
    if (qc > QW) qc = QW;
    for (int qi = lane; qi < qc; qi += 64) {
        unsigned e = qbuf[wave][qi];
        int m = (int)(e >> 9), n = (int)(e & 511u);
        const float4* er = (const float4*)(embed + n * VQ_D);
        const float* xr = &Xs32[wave][m * X32_STR];
        float dot = 0.f;
#pragma unroll
        for (int d4 = 0; d4 < 16; ++d4) {
            float4 ev = er[d4];
            dot = fmaf(xr[4 * d4 + 0], ev.x, dot);
            dot = fmaf(xr[4 * d4 + 1], ev.y, dot);
            dot = fmaf(xr[4 * d4 + 2], ev.z, dot);
            dot = fmaf(xr[4 * d4 + 3], ev.w, dot);
        }
        float v = fmaf(-2.f, dot, esq[n]);
        unsigned long long key =
            (((unsigned long long)fenc(v)) << 32) | (unsigned)n;
        atomicMin(&row_best[wave][m], key);  // exact; tie -> smaller n
    }
    asm volatile("s_waitcnt lgkmcnt(0)");   // all this wave's atomics done

    // ---- epilogue (wave-private): indices + coalesced quantized rows ----
    if (lane < WROWS)
        out_idx[n0 + lane] =
            (float)(unsigned)(row_best[wave][lane] & 0xffffffffu);

#pragma unroll
    for (int it = 0; it < 8; ++it) {
        int o   = it * 256 + lane * 4;   // 32 rows x 64 floats, contiguous
        int row = o >> 6;
        int col = o & 63;
        unsigned k = (unsigned)(row_best[wave][row] & 0xffffffffu);
        float4 val = *(const float4*)(embed + k * VQ_D + col);
        *(float4*)(out_q + (size_t)n0 * VQ_D + o) = val;
    }
}

extern "C" void kernel_launch(void* const* d_in, const int* in_sizes, int n_in,
                              void* d_out, int out_size, void* d_ws, size_t ws_size,
                              hipStream_t stream) {
    const float* x     = (const float*)d_in[0];
    const float* embed = (const float*)d_in[1];
    float* out_q   = (float*)d_out;
    float* out_idx = (float*)d_out + (size_t)VQ_N * VQ_D;

    float* esq     = (float*)d_ws;                          // 512 f
    _Float16* EH2  = (_Float16*)((char*)d_ws + 2048);       // 32768 f16

    vq_prep_kernel<<<(VQ_K * VQ_D) / 256, 256, 0, stream>>>(embed, EH2, esq);
    vq_wave_kernel<<<VQ_N / (WROWS * NW), 256, 0, stream>>>(
        x, embed, esq, EH2, out_q, out_idx);
}